// Round 8
// baseline (1280.657 us; speedup 1.0000x reference)
//
#include <hip/hip_runtime.h>

#define NENT 40000
#define NB 128
#define NQ 24
#define NOPS 12
#define EPO 300000
#define NTOT (NOPS * EPO)
#define NRANK 3
#define NPASS 8
#define CP 16       // batch columns per pass
#define ECAP 160    // ELL row capacity (Poisson(90) max over 40K rows << 160)
#define SEG 5000    // entity segment per fused01 block (8 segs)

typedef float v4f __attribute__((ext_vector_type(4)));

__device__ __forceinline__ v4f shfl_xor4(v4f x, int m) {
    v4f r;
    r.x = __shfl_xor(x.x, m);
    r.y = __shfl_xor(x.y, m);
    r.z = __shfl_xor(x.z, m);
    r.w = __shfl_xor(x.w, m);
    return r;
}

__device__ __forceinline__ bool bittest(const unsigned* bm, int i) {
    return (bm[i >> 5] >> (i & 31)) & 1u;
}

// ---------------- bitmaps: heads and heads ∪ N_out(heads) ----------------
__global__ void headmark_kernel(const int* __restrict__ heads, unsigned* __restrict__ bmH,
                                unsigned* __restrict__ bm2) {
    int h = heads[threadIdx.x];
    atomicOr(&bmH[h >> 5], 1u << (h & 31));
    atomicOr(&bm2[h >> 5], 1u << (h & 31));
}

__global__ void mark2_kernel(const int* __restrict__ src, const int* __restrict__ dst,
                             const unsigned* __restrict__ bmH, unsigned* __restrict__ bm2) {
    int i = blockIdx.x * 256 + threadIdx.x;
    if (i < NTOT) {
        int s = __builtin_nontemporal_load(&src[i]);
        if (bittest(bmH, s)) {
            int d = dst[i];
            atomicOr(&bm2[d >> 5], 1u << (d & 31));
        }
    }
}

// ---------------- single-pass ELL build: dst always; src gated on bm2 ----------------
__global__ void build_ell_kernel(const int* __restrict__ src, const int* __restrict__ dst,
                                 const float* __restrict__ val, const unsigned* __restrict__ bm2,
                                 int* __restrict__ fillD, int* __restrict__ fillS,
                                 int2* __restrict__ eD, int2* __restrict__ eS) {
    int i = blockIdx.x * 256 + threadIdx.x;
    if (i >= NTOT) return;
    int s = __builtin_nontemporal_load(&src[i]);
    int d = __builtin_nontemporal_load(&dst[i]);
    int v = __builtin_nontemporal_load((const int*)&val[i]);
    int op = i / EPO;   // compile-time magic-mul
    int pd = atomicAdd(&fillD[d], 1);
    eD[(size_t)d * ECAP + pd] = make_int2(s | (op << 16), v);
    if (bittest(bm2, s)) {
        int ps = atomicAdd(&fillS[s], 1);
        eS[(size_t)s * ECAP + ps] = make_int2(d | (op << 16), v);
    }
}

// pad eD rows to multiple of 16 with zero-val edges; update fillD to padded length
__global__ void pad_kernel(int* __restrict__ fillD, int2* __restrict__ eD) {
    int j = blockIdx.x * 256 + threadIdx.x;
    if (j >= NENT) return;
    int l = fillD[j];
    int lp = (l + 15) & ~15;
    int2* row = eD + (size_t)j * ECAP;
    for (int k = l; k < lp; ++k) row[k] = make_int2(0, 0);
    fillD[j] = lp;
}

// ---------------- LSTM (deduped over 24 distinct query values), zx fused ----------------
__global__ void lstm_all_kernel(const float* __restrict__ emb,
                                const float* __restrict__ Wih_f, const float* __restrict__ bih_f,
                                const float* __restrict__ bhh_f,
                                const float* __restrict__ Wih_b, const float* __restrict__ bih_b,
                                const float* __restrict__ bhh_b,
                                const float* __restrict__ Whh_f, const float* __restrict__ Whh_b,
                                float* __restrict__ hq) {
    int combo = blockIdx.x / NQ;
    int q = blockIdx.x % NQ;
    int dir = combo / 3, r = combo % 3;
    const float* Wih = (dir ? Wih_b : Wih_f) + r * 512 * 128;
    const float* bih = (dir ? bih_b : bih_f) + r * 512;
    const float* bhh = (dir ? bhh_b : bhh_f) + r * 512;
    const float* Whh = (dir ? Whh_b : Whh_f) + r * 512 * 128;
    __shared__ float x[128];
    __shared__ float h[128];
    int u = threadIdx.x;
    x[u] = emb[q * 128 + u];
    __syncthreads();
    float a0 = 0.f, a1 = 0.f, a2 = 0.f, a3 = 0.f;
    {
        const float* W0p = Wih + u * 128;
        const float* W1p = Wih + (128 + u) * 128;
        const float* W2p = Wih + (256 + u) * 128;
        const float* W3p = Wih + (384 + u) * 128;
        for (int d = 0; d < 128; ++d) {
            float xv = x[d];
            a0 = fmaf(xv, W0p[d], a0);
            a1 = fmaf(xv, W1p[d], a1);
            a2 = fmaf(xv, W2p[d], a2);
            a3 = fmaf(xv, W3p[d], a3);
        }
    }
    float zi0 = a0 + bih[u] + bhh[u];
    float zf0 = a1 + bih[128 + u] + bhh[128 + u];
    float zg0 = a2 + bih[256 + u] + bhh[256 + u];
    float zo0 = a3 + bih[384 + u] + bhh[384 + u];
    const float* Wi = Whh + u * 128;
    const float* Wf = Whh + (128 + u) * 128;
    const float* Wg = Whh + (256 + u) * 128;
    const float* Wo = Whh + (384 + u) * 128;
    float c = 0.f;
    h[u] = 0.f;
    for (int s = 0; s < 3; ++s) {
        __syncthreads();
        float b0v = 0.f, b1v = 0.f, b2v = 0.f, b3v = 0.f;
        for (int d = 0; d < 128; ++d) {
            float hv = h[d];
            b0v = fmaf(hv, Wi[d], b0v);
            b1v = fmaf(hv, Wf[d], b1v);
            b2v = fmaf(hv, Wg[d], b2v);
            b3v = fmaf(hv, Wo[d], b3v);
        }
        float ig = 1.f / (1.f + expf(-(zi0 + b0v)));
        float fg = 1.f / (1.f + expf(-(zf0 + b1v)));
        float gg = tanhf(zg0 + b2v);
        float og = 1.f / (1.f + expf(-(zo0 + b3v)));
        c = fg * c + ig * gg;
        float hn = og * tanhf(c);
        __syncthreads();
        h[u] = hn;
        hq[(size_t)((combo * 3 + s) * NQ + q) * 128 + u] = hn;
    }
}

__global__ void attnq_kernel(const float* __restrict__ hq, const float* __restrict__ W0,
                             const float* __restrict__ b0, float* __restrict__ attnq) {
    int r = blockIdx.x / 3, t = blockIdx.x % 3;
    __shared__ float W0s[256 * 13];
    for (int idx = threadIdx.x; idx < 256 * 13; idx += 32) W0s[idx] = W0[idx];
    __syncthreads();
    int q = threadIdx.x;
    if (q >= NQ) return;
    float acc[13];
    for (int k = 0; k < 13; ++k) acc[k] = b0[k];
    const float* hf = hq + (size_t)(((0 * 3 + r) * 3 + t) * NQ + q) * 128;
    const float* hb = hq + (size_t)(((1 * 3 + r) * 3 + (2 - t)) * NQ + q) * 128;
    for (int u = 0; u < 128; ++u) {
        float v = hf[u];
        for (int k = 0; k < 13; ++k) acc[k] = fmaf(v, W0s[u * 13 + k], acc[k]);
    }
    for (int u = 0; u < 128; ++u) {
        float v = hb[u];
        for (int k = 0; k < 13; ++k) acc[k] = fmaf(v, W0s[(128 + u) * 13 + k], acc[k]);
    }
    float m = acc[0];
    for (int k = 1; k < 13; ++k) m = fmaxf(m, acc[k]);
    float e[13];
    float sum = 0.f;
    for (int k = 0; k < 13; ++k) { e[k] = expf(acc[k] - m); sum += e[k]; }
    float inv = 1.f / sum;
    float* ao = attnq + (size_t)(r * 3 + t) * 13 * NQ;
    for (int k = 0; k < 13; ++k) ao[k * NQ + q] = e[k] * inv;
}

__global__ void expand_kernel(const int* __restrict__ queries, const float* __restrict__ attnq,
                              float* __restrict__ attn) {
    __shared__ int qs[128];
    if (threadIdx.x < 128) qs[threadIdx.x] = queries[threadIdx.x];
    __syncthreads();
    for (int idx = threadIdx.x; idx < 9 * 13 * 128; idx += 256) {
        int b = idx & 127, kk = idx >> 7;
        attn[idx] = attnq[kk * NQ + qs[b]];
    }
}

// ---------------- steps 0+1: LDS accumulation, all 3 ranks per block; dense writes ----------------
// block = (b, seg); LDS holds acc[3][SEG]; walk shared across ranks; no global atomics, no memset.
__global__ __launch_bounds__(256) void fused01_kernel(const int* __restrict__ heads,
                                                      const float* __restrict__ attn,
                                                      const int* __restrict__ fillS,
                                                      const int2* __restrict__ eS,
                                                      float* __restrict__ mem2) {
    __shared__ float acc3[3][SEG];
    __shared__ float c0s[3][13], c1s[3][13];
    int b = blockIdx.x;
    int seg = blockIdx.y;
    int base = seg * SEG;
    int tid = threadIdx.x;
    if (tid < 39) {
        int r = tid / 13, k = tid % 13;
        c0s[r][k] = attn[(size_t)((r * 3 + 0) * 13 + k) * 128 + b];
        c1s[r][k] = attn[(size_t)((r * 3 + 1) * 13 + k) * 128 + b];
    }
    for (int k = tid; k < 3 * SEG; k += 256) ((float*)acc3)[k] = 0.f;
    __syncthreads();
    int h = heads[b];
    int lenH = fillS[h];
    for (int ent = tid; ent < lenH + 1; ent += 256) {
        int i;
        float wv0, wv1, wv2;
        if (ent == 0) {
            i = h;
            wv0 = c0s[0][12]; wv1 = c0s[1][12]; wv2 = c0s[2][12];
        } else {
            int2 e = eS[(size_t)h * ECAP + ent - 1];
            i = e.x & 0xFFFF;
            float v = __int_as_float(e.y);
            int op = e.x >> 16;
            wv0 = v * c0s[0][op]; wv1 = v * c0s[1][op]; wv2 = v * c0s[2][op];
        }
        unsigned ti = (unsigned)(i - base);
        if (ti < SEG) {   // step-1 identity
            atomicAdd(&acc3[0][ti], c1s[0][12] * wv0);
            atomicAdd(&acc3[1][ti], c1s[1][12] * wv1);
            atomicAdd(&acc3[2][ti], c1s[2][12] * wv2);
        }
        int lenI = fillS[i];
        const int2* ei = eS + (size_t)i * ECAP;
        for (int f = 0; f < lenI; ++f) {
            int2 e2 = ei[f];
            unsigned t = (unsigned)((e2.x & 0xFFFF) - base);
            if (t < SEG) {
                float v2 = __int_as_float(e2.y);
                int op2 = e2.x >> 16;
                atomicAdd(&acc3[0][t], v2 * c1s[0][op2] * wv0);
                atomicAdd(&acc3[1][t], v2 * c1s[1][op2] * wv1);
                atomicAdd(&acc3[2][t], v2 * c1s[2][op2] * wv2);
            }
        }
    }
    __syncthreads();
    int p = b >> 4, c = b & 15;
#pragma unroll
    for (int r = 0; r < 3; ++r) {
        float* dst = mem2 + ((size_t)(r * NPASS + p) * NENT + base) * CP + c;
        for (int k = tid; k < SEG; k += 256) dst[(size_t)k * CP] = acc3[r][k];
    }
}

// ---------------- step 2: dense gather; XCD-pinned pass; padded rows => uniform branches ----------------
__global__ __launch_bounds__(256) void dense_kernel(const float* __restrict__ attn,
                                                    const int* __restrict__ fillD,
                                                    const int2* __restrict__ edgesD,
                                                    const float* __restrict__ in,
                                                    float* __restrict__ out,
                                                    float* __restrict__ normv) {
    int p = blockIdx.x;   // pass = XCD (linear-id % 8 round-robin)
    int r = blockIdx.z;
    __shared__ __align__(16) float cs[13 * 20];   // stride 20 floats: rows 16B-aligned
    __shared__ float npart[4][16];
    int tid = threadIdx.x;
    if (tid < 13 * 16) {
        int op = tid >> 4, c0 = tid & 15;
        cs[op * 20 + c0] = attn[(size_t)((r * 3 + 2) * 13 + op) * 128 + p * CP + c0];
    }
    __syncthreads();
    int wave = tid >> 6, lane = tid & 63;
    int slot = lane >> 2;        // 16 edge slots
    int cq4 = (lane & 3) * 4;    // 4 cols per lane
    int jw = blockIdx.y * 32 + wave * 8;
    const float* inr = in + (size_t)(r * NPASS + p) * NENT * CP;
    float* outr = out + (size_t)(r * NPASS + p) * NENT * CP;
    int lens[8];
#pragma unroll
    for (int i = 0; i < 8; ++i) lens[i] = fillD[jw + i];   // padded: multiple of 16
    v4f cid = *(const v4f*)&cs[12 * 20 + cq4];
    v4f rsum = (v4f)0.f;
#pragma unroll
    for (int rr = 0; rr < 8; ++rr) {
        int j = jw + rr;
        int len = lens[rr];                       // wave-uniform
        const int2* ed = edgesD + (size_t)j * ECAP;
        v4f a = (v4f)0.f;
        int i = slot;
        for (; i + 48 < len; i += 64) {           // 4 independent edges in flight, no masks
            int2 e0 = ed[i];
            int2 e1 = ed[i + 16];
            int2 e2 = ed[i + 32];
            int2 e3 = ed[i + 48];
            v4f g0 = *(const v4f*)(inr + (size_t)(e0.x & 0xFFFF) * CP + cq4);
            v4f g1 = *(const v4f*)(inr + (size_t)(e1.x & 0xFFFF) * CP + cq4);
            v4f g2 = *(const v4f*)(inr + (size_t)(e2.x & 0xFFFF) * CP + cq4);
            v4f g3 = *(const v4f*)(inr + (size_t)(e3.x & 0xFFFF) * CP + cq4);
            v4f c0 = *(const v4f*)&cs[(e0.x >> 16) * 20 + cq4];
            v4f c1 = *(const v4f*)&cs[(e1.x >> 16) * 20 + cq4];
            v4f c2 = *(const v4f*)&cs[(e2.x >> 16) * 20 + cq4];
            v4f c3 = *(const v4f*)&cs[(e3.x >> 16) * 20 + cq4];
            a += (__int_as_float(e0.y) * c0) * g0;
            a += (__int_as_float(e1.y) * c1) * g1;
            a += (__int_as_float(e2.y) * c2) * g2;
            a += (__int_as_float(e3.y) * c3) * g3;
        }
        for (; i < len; i += 16) {                // <=3 uniform remainder chunks
            int2 e0 = ed[i];
            v4f g0 = *(const v4f*)(inr + (size_t)(e0.x & 0xFFFF) * CP + cq4);
            v4f c0 = *(const v4f*)&cs[(e0.x >> 16) * 20 + cq4];
            a += (__int_as_float(e0.y) * c0) * g0;
        }
        a += shfl_xor4(a, 4);
        a += shfl_xor4(a, 8);
        a += shfl_xor4(a, 16);
        a += shfl_xor4(a, 32);
        if (slot == 0) {
            v4f mi = *(const v4f*)(inr + (size_t)j * CP + cq4);
            v4f res = cid * mi + a;
            *(v4f*)(outr + (size_t)j * CP + cq4) = res;
            rsum += res;
        }
    }
    if (slot == 0) *(v4f*)&npart[wave][cq4] = rsum;
    __syncthreads();
    if (tid < 16) {
        float s = npart[0][tid] + npart[1][tid] + npart[2][tid] + npart[3][tid];
        atomicAdd(&normv[r * 128 + p * CP + tid], s);
    }
}

// ---------------- epilogue: rnorm inlined into final ----------------
__global__ void final_kernel(const float* __restrict__ mem3, const float* __restrict__ normv,
                             float* __restrict__ out) {
    __shared__ float tile[32 * 129];
    __shared__ float rn[384];
    for (int idx = threadIdx.x; idx < 384; idx += 256)
        rn[idx] = 1.f / fmaxf(normv[idx], 1e-20f);
    __syncthreads();
    int j0 = blockIdx.x * 32;
    for (int p = 0; p < NPASS; ++p) {
        for (int it = 0; it < 2; ++it) {
            int lin = it * 256 + threadIdx.x;
            int jj = lin >> 4, c = lin & 15;
            int b = p * CP + c;
            float s = 0.f;
            for (int r = 0; r < 3; ++r)
                s += mem3[((size_t)(r * NPASS + p) * NENT + j0 + jj) * CP + c] * rn[r * 128 + b];
            tile[jj * 129 + b] = s;
        }
    }
    __syncthreads();
    for (int it = 0; it < 16; ++it) {
        int lin = it * 256 + threadIdx.x;
        int b = lin >> 5, jj = lin & 31;
        out[(size_t)b * NENT + j0 + jj] = tile[jj * 129 + b];
    }
}

extern "C" void kernel_launch(void* const* d_in, const int* in_sizes, int n_in,
                              void* d_out, int out_size, void* d_ws, size_t ws_size,
                              hipStream_t stream) {
    const int*   queries  = (const int*)d_in[0];
    const int*   heads    = (const int*)d_in[1];
    const int*   edge_src = (const int*)d_in[2];
    const int*   edge_dst = (const int*)d_in[3];
    const float* edge_val = (const float*)d_in[4];
    const float* emb      = (const float*)d_in[5];
    const float* Wih_f    = (const float*)d_in[6];
    const float* Whh_f    = (const float*)d_in[7];
    const float* bih_f    = (const float*)d_in[8];
    const float* bhh_f    = (const float*)d_in[9];
    const float* Wih_b    = (const float*)d_in[10];
    const float* Whh_b    = (const float*)d_in[11];
    const float* bih_b    = (const float*)d_in[12];
    const float* bhh_b    = (const float*)d_in[13];
    const float* W0       = (const float*)d_in[14];
    const float* b0       = (const float*)d_in[15];
    float* out = (float*)d_out;

    char* w = (char*)d_ws;
    size_t off = 0;
    auto alloc = [&](size_t bytes) -> void* {
        off = (off + 255) & ~(size_t)255;
        void* p = w + off;
        off += bytes;
        return p;
    };
    float* attnq  = (float*)alloc((size_t)9 * 13 * NQ * sizeof(float));
    float* attn   = (float*)alloc((size_t)9 * 13 * 128 * sizeof(float));
    float* hq     = (float*)alloc((size_t)6 * 3 * NQ * 128 * sizeof(float));
    // meta block (single memset): bmH | bm2 | fillD | fillS
    unsigned* bmH = (unsigned*)alloc((2 * 1250 + 2 * NENT) * sizeof(int));
    unsigned* bm2 = bmH + 1250;
    int* fillD    = (int*)(bm2 + 1250);
    int* fillS    = fillD + NENT;
    int2*  eD     = (int2*)alloc((size_t)NENT * ECAP * sizeof(int2));
    float* mem2   = (float*)alloc((size_t)NRANK * NENT * NB * sizeof(float));
    float* mem3   = (float*)alloc((size_t)NRANK * NENT * NB * sizeof(float));
    int2*  eS     = (int2*)mem3;   // alias: eS lifetime (build..fused01) ends before mem3's (dense..final)
    float* normv  = (float*)alloc((size_t)NRANK * NB * sizeof(float));

    int cooGrid = (NTOT + 255) / 256;

    // bitmaps + fills (one memset), then single-pass ELL build + pad
    hipMemsetAsync(bmH, 0, (2 * 1250 + 2 * NENT) * sizeof(int), stream);
    headmark_kernel<<<1, 128, 0, stream>>>(heads, bmH, bm2);
    mark2_kernel<<<cooGrid, 256, 0, stream>>>(edge_src, edge_dst, bmH, bm2);
    build_ell_kernel<<<cooGrid, 256, 0, stream>>>(edge_src, edge_dst, edge_val, bm2,
                                                  fillD, fillS, eD, eS);
    pad_kernel<<<(NENT + 255) / 256, 256, 0, stream>>>(fillD, eD);

    // LSTM + attention (deduped over 24 queries)
    lstm_all_kernel<<<6 * NQ, 128, 0, stream>>>(emb, Wih_f, bih_f, bhh_f,
                                                Wih_b, bih_b, bhh_b, Whh_f, Whh_b, hq);
    attnq_kernel<<<9, 32, 0, stream>>>(hq, W0, b0, attnq);
    expand_kernel<<<1, 256, 0, stream>>>(queries, attnq, attn);

    // steps 0+1 (LDS-accumulated, writes mem2 densely -> no memset), step 2 dense
    hipMemsetAsync(normv, 0, NRANK * NB * sizeof(float), stream);
    {
        dim3 g(NB, NENT / SEG);
        fused01_kernel<<<g, 256, 0, stream>>>(heads, attn, fillS, eS, mem2);
    }
    {
        dim3 g(NPASS, NENT / 32, NRANK);
        dense_kernel<<<g, 256, 0, stream>>>(attn, fillD, eD, mem2, mem3, normv);
    }

    // epilogue (rnorm fused into final)
    final_kernel<<<NENT / 32, 256, 0, stream>>>(mem3, normv, out);
}